// Round 10
// baseline (362.571 us; speedup 1.0000x reference)
//
#include <hip/hip_runtime.h>
#include <stdint.h>
#include <stddef.h>

typedef __bf16 bf16;
typedef __bf16 bf16x4 __attribute__((ext_vector_type(4)));
typedef __bf16 bf16x8 __attribute__((ext_vector_type(8)));
typedef float f32x4 __attribute__((ext_vector_type(4)));
typedef float f32x16 __attribute__((ext_vector_type(16)));

#define BNI 0.9999950000374996f  // 1/sqrt(1+1e-5)
#define NROW 240                  // rows per block (12 polylines x 20)
#define TOTROW 163840
#define NPOLY 8192

// swizzled act addressing: row-major stride 256 bf16, 16B chunks XOR-swizzled by row
#define AADDR(r, ch) ((r)*256 + ((((ch) ^ ((r)&31)))<<3))

// dynamic LDS layout (bytes)
#define OFF_ACT 0                 // 240*512 = 122880 (sAct; also sY rows 0..31 in out phase)
#define OFF_WB  122880            // 64*512  = 32768  (weight chunk; also pooled tile 32 rows)
#define OFF_T2  155648            // 12*512  = 6144   (t2, bf16, flat rows)
#define OFF_VAL 161792            // 12*4 = 48
#define LDS_TOTAL 161840

// ws layout (bf16 elems) — folded weights
#define WS_PRE_W0 0
#define WS_PRE_W1 8192
#define WS_PRE_W2 73728
#define WS_MLP_W0 139264
#define WS_MLP_W1 270336
#define WS_MLP_W2 335872
#define WS_OUT_W0 401408
#define WS_OUT_W1 466944

__device__ __forceinline__ bf16 f2b(float f){
  unsigned int i = __builtin_bit_cast(unsigned int, f);
  unsigned int r = i + 0x7fffu + ((i >> 16) & 1u);
  unsigned short h = (unsigned short)(r >> 16);
  return __builtin_bit_cast(bf16, h);
}
__device__ __forceinline__ float b2f(bf16 x){
  unsigned short u = __builtin_bit_cast(unsigned short, x);
  union { unsigned int i; float f; } v; v.i = ((unsigned int)u) << 16; return v.f;
}
__device__ __forceinline__ bf16x8 ld8f(const float* p, float sc){
  f32x4 a = *(const f32x4*)p;
  f32x4 b = *(const f32x4*)(p + 4);
  bf16x8 r;
  #pragma unroll
  for (int j = 0; j < 4; ++j){ r[j] = f2b(a[j]*sc); r[4+j] = f2b(b[j]*sc); }
  return r;
}

// ---------------- prep: fp32 weights -> bf16 in ws, BN scale folded ----------------
__global__ __launch_bounds__(256)
void prep_kernel(const float* s0, const float* s1, const float* s2, const float* s3,
                 const float* s4, const float* s5, const float* s6, const float* s7,
                 const float* g0, const float* g1, const float* g3, const float* g4,
                 bf16* dst)
{
  const int offs[8] = {WS_PRE_W0, WS_PRE_W1, WS_PRE_W2, WS_MLP_W0,
                       WS_MLP_W1, WS_MLP_W2, WS_OUT_W0, WS_OUT_W1};
  const int sz[8]   = {8192, 65536, 65536, 131072, 65536, 65536, 65536, 65536};
  const int ld[8]   = {32, 256, 256, 512, 256, 256, 256, 256};
  int r = blockIdx.y;
  const float* src = s0;
  if (r == 1) src = s1; else if (r == 2) src = s2; else if (r == 3) src = s3;
  else if (r == 4) src = s4; else if (r == 5) src = s5; else if (r == 6) src = s6;
  else if (r == 7) src = s7;
  const float* gp = (r==0)?g0:(r==1)?g1:(r==3)?g3:(r==4)?g4:nullptr;
  int i = (blockIdx.x*256 + threadIdx.x)*8;
  if (i < sz[r]){
    float sc = gp ? gp[i/ld[r]]*BNI : 1.0f;   // i..i+7 same row (ld % 8 == 0)
    *(bf16x8*)&dst[offs[r] + i] = ld8f(src + i, sc);
  }
}

// ---------------- main kernel helpers ----------------
// stage one 64-feature chunk (64x256 k, 32 KB) global->regs->LDS (swizzled)
__device__ __forceinline__ void stageLoad(bf16x8* v, const bf16* W, int ldK, int c64, int tid){
  #pragma unroll
  for (int i = 0; i < 8; ++i){
    int id = tid + 256*i;             // 2048 chunks exactly
    int fr = id >> 5, kc = id & 31;
    v[i] = *(const bf16x8*)(W + (size_t)(c64*64 + fr)*ldK + kc*8);
  }
}
__device__ __forceinline__ void stageStore(const bf16x8* v, bf16* wbuf, int tid){
  #pragma unroll
  for (int i = 0; i < 8; ++i){
    int id = tid + 256*i;
    int fr = id >> 5, kc = id & 31;
    *(bf16x8*)&wbuf[fr*256 + ((kc ^ (fr & 31))<<3)] = v[i];
  }
}

// transposed epilogue: lane owns row `row`; features f0..f0+3 per quad -> b64 act writes
template<int RELU, int MASK, int ADDT2>
__device__ __forceinline__ void epiT(
    const f32x16& acc, int nt, int row, int poly, float mk, bool valid,
    bf16* sAct, const bf16* sT2, const float* bptr, int hi)
{
  #pragma unroll
  for (int q2 = 0; q2 < 4; ++q2){
    int f0 = nt*32 + 8*q2 + 4*hi;
    f32x4 bb = *(const f32x4*)(bptr + f0);
    bf16x4 tv = {};
    if (ADDT2) tv = *(const bf16x4*)&sT2[poly*256 + f0];
    bf16x4 o;
    #pragma unroll
    for (int j = 0; j < 4; ++j){
      float v = acc[4*q2 + j];
      if (ADDT2) v += b2f(tv[j]);
      v += bb[j];
      if (RELU) v = fmaxf(v, 0.0f);
      if (MASK) v *= mk;
      o[j] = f2b(v);
    }
    if (valid)
      *(bf16x4*)&sAct[row*256 + (((nt*4 + q2) ^ (row & 31))<<3) + 4*hi] = o;
  }
}

// 256->256 layer, transposed (W as A-operand, acts held in regs for 2 row-tiles)
template<int RELU, int MASK, int ADDT2>
__device__ __forceinline__ void layerT(
    bf16* sAct, bf16* wbuf, const bf16* sT2,
    const bf16* W, int ldK, const float* bptr,
    const int* maskp, int blk, int w, int lane32, int hi, int tid)
{
  const int row0 = w*64 + lane32, row1 = w*64 + 32 + lane32;
  bf16x8 B0[16], B1[16];
  #pragma unroll
  for (int t = 0; t < 16; ++t){
    B0[t] = *(const bf16x8*)&sAct[AADDR(row0, 2*t + hi)];
    B1[t] = *(const bf16x8*)&sAct[AADDR(row1, 2*t + hi)];
  }
  float mk0 = 1.0f, mk1 = 1.0f;
  if (MASK){
    int g0 = blk*NROW + row0;
    mk0 = (g0 < TOTROW && maskp[g0]) ? 1.0f : 0.0f;
    int g1 = blk*NROW + row1;
    mk1 = (row1 < NROW && g1 < TOTROW && maskp[g1]) ? 1.0f : 0.0f;
  }
  const int poly0 = row0/20;
  const int poly1 = (row1 < NROW ? row1 : 0)/20;   // clamp: keep sT2 reads in-bounds

  bf16x8 st[8];
  stageLoad(st, W, ldK, 0, tid);
  __syncthreads();                    // wbuf free (prior phase compute done)
  stageStore(st, wbuf, tid);
  #pragma unroll 1
  for (int c = 0; c < 4; ++c){
    __syncthreads();                  // chunk c staged
    if (c < 3) stageLoad(st, W, ldK, c + 1, tid);   // loads fly under compute
    #pragma unroll
    for (int h2 = 0; h2 < 2; ++h2){
      int nt = c*2 + h2;
      f32x16 a0 = {}, a1 = {};
      #pragma unroll
      for (int t = 0; t < 16; ++t){
        int fr = h2*32 + lane32;
        bf16x8 wf = *(const bf16x8*)&wbuf[fr*256 + (((2*t + hi) ^ (fr & 31))<<3)];
        a0 = __builtin_amdgcn_mfma_f32_32x32x16_bf16(wf, B0[t], a0, 0, 0, 0);
        a1 = __builtin_amdgcn_mfma_f32_32x32x16_bf16(wf, B1[t], a1, 0, 0, 0);
      }
      epiT<RELU,MASK,ADDT2>(a0, nt, row0, poly0, mk0, true, sAct, sT2, bptr, hi);
      epiT<RELU,MASK,ADDT2>(a1, nt, row1, poly1, mk1, row1 < NROW, sAct, sT2, bptr, hi);
    }
    if (c < 3){ __syncthreads(); stageStore(st, wbuf, tid); }  // readers done -> overwrite
  }
}

// pool 20 rows per polyline -> sPool rows 0..11 (swizzled); garbage rows finite
__device__ __forceinline__ void poolT(const bf16* sAct, bf16* sPool, int tid){
  #pragma unroll
  for (int i = 0; i < 2; ++i){
    int id = tid + 256*i;
    if (id < 384){
      int poly = id >> 5, c = id & 31;
      float m[8];
      bf16x8 v0 = *(const bf16x8*)&sAct[AADDR(poly*20, c)];
      #pragma unroll
      for (int j = 0; j < 8; ++j) m[j] = b2f(v0[j]);
      for (int r = 1; r < 20; ++r){
        bf16x8 v = *(const bf16x8*)&sAct[AADDR(poly*20 + r, c)];
        #pragma unroll
        for (int j = 0; j < 8; ++j) m[j] = fmaxf(m[j], b2f(v[j]));
      }
      bf16x8 o;
      #pragma unroll
      for (int j = 0; j < 8; ++j) o[j] = f2b(m[j]);
      *(bf16x8*)&sPool[AADDR(poly, c)] = o;
    }
  }
}

__global__ __launch_bounds__(256, 1)
void traj_kernel(const float* __restrict__ poly, const int* __restrict__ maskp,
                 const float* pre_b0, const float* pre_b1, const float* pre_bias2,
                 const float* mlp_b0, const float* mlp_b1, const float* mlp_bias2,
                 const float* out_b0, const float* out_b1,
                 const bf16* __restrict__ ws,
                 float* __restrict__ outp)
{
  extern __shared__ char smem[];
  bf16*  sAct   = (bf16*)(smem + OFF_ACT);
  bf16*  wbuf   = (bf16*)(smem + OFF_WB);
  bf16*  sPool  = wbuf;                      // pooled tile aliases wbuf (barrier-separated)
  bf16*  sT2    = (bf16*)(smem + OFF_T2);
  float* sValid = (float*)(smem + OFF_VAL);
  bf16*  sY     = sAct;                      // y tile aliases sAct (dead after pool2)

  const int tid = threadIdx.x;
  const int w = tid >> 6, L = tid & 63, lane32 = L & 31, hi = L >> 5;
  const int row0 = w*64 + lane32, row1 = w*64 + 32 + lane32;
  const int blk = blockIdx.x;

  const bf16* pw0 = ws + WS_PRE_W0;
  const bf16* pw1 = ws + WS_PRE_W1;
  const bf16* pw2 = ws + WS_PRE_W2;
  const bf16* mw0 = ws + WS_MLP_W0;
  const bf16* mw1 = ws + WS_MLP_W1;
  const bf16* mw2 = ws + WS_MLP_W2;
  const bf16* ow0 = ws + WS_OUT_W0;
  const bf16* ow1 = ws + WS_OUT_W1;

  // ---- phase 0: input (240x32 fp32 -> bf16, swizzled; OOB rows zero) + valid flags ----
  #pragma unroll
  for (int i = 0; i < 4; ++i){
    int id = tid + 256*i;
    if (id < 960){
      int row = id >> 2, c = id & 3;
      int grow = blk*NROW + row;
      bf16x8 v = {};
      if (grow < TOTROW) v = ld8f(poly + (size_t)grow*32 + c*8, 1.0f);
      *(bf16x8*)&sAct[AADDR(row, c)] = v;
    }
  }
  if (tid < 12){
    float v = 0.0f;
    #pragma unroll
    for (int r = 0; r < 20; ++r){
      int g = blk*NROW + tid*20 + r;
      if (g < TOTROW && maskp[g]) v = 1.0f;
    }
    sValid[tid] = v;
  }
  __syncthreads();

  // ---- pre0: K=32, W direct from ws (folded), transposed ----
  {
    bf16x8 Bp0[2], Bp1[2];
    #pragma unroll
    for (int t = 0; t < 2; ++t){
      Bp0[t] = *(const bf16x8*)&sAct[AADDR(row0, 2*t + hi)];
      Bp1[t] = *(const bf16x8*)&sAct[AADDR(row1, 2*t + hi)];
    }
    #pragma unroll 1
    for (int nt = 0; nt < 8; ++nt){
      f32x16 a0 = {}, a1 = {};
      #pragma unroll
      for (int t = 0; t < 2; ++t){
        bf16x8 wf = *(const bf16x8*)(pw0 + (size_t)(nt*32 + lane32)*32 + 16*t + 8*hi);
        a0 = __builtin_amdgcn_mfma_f32_32x32x16_bf16(wf, Bp0[t], a0, 0, 0, 0);
        a1 = __builtin_amdgcn_mfma_f32_32x32x16_bf16(wf, Bp1[t], a1, 0, 0, 0);
      }
      epiT<1,0,0>(a0, nt, row0, 0, 1.0f, true, sAct, sT2, pre_b0, hi);
      epiT<1,0,0>(a1, nt, row1, 0, 1.0f, row1 < NROW, sAct, sT2, pre_b0, hi);
    }
  }

  // ---- pre1, pre2 ----
  layerT<1,0,0>(sAct, wbuf, sT2, pw1, 256, pre_b1,    maskp, blk, w, lane32, hi, tid);
  layerT<0,1,0>(sAct, wbuf, sT2, pw2, 256, pre_bias2, maskp, blk, w, lane32, hi, tid);

  __syncthreads();                    // pre2 compute done
  poolT(sAct, sPool, tid);
  __syncthreads();                    // pool1 visible

  // ---- t2 = pooled @ mlp_w0'[:,256:]^T (folded), weights direct global ----
  {
    bf16x8 Bp[16];
    #pragma unroll
    for (int t = 0; t < 16; ++t)
      Bp[t] = *(const bf16x8*)&sPool[AADDR(lane32, 2*t + hi)];
    #pragma unroll 1
    for (int m = 0; m < 2; ++m){
      int nt = w*2 + m;
      f32x16 acc = {};
      #pragma unroll
      for (int t = 0; t < 16; ++t){
        bf16x8 wf = *(const bf16x8*)(mw0 + (size_t)(nt*32 + lane32)*512 + 256 + 16*t + 8*hi);
        acc = __builtin_amdgcn_mfma_f32_32x32x16_bf16(wf, Bp[t], acc, 0, 0, 0);
      }
      if (lane32 < 12){
        #pragma unroll
        for (int q2 = 0; q2 < 4; ++q2){
          int f0 = nt*32 + 8*q2 + 4*hi;
          bf16x4 o;
          #pragma unroll
          for (int j = 0; j < 4; ++j) o[j] = f2b(acc[4*q2 + j]);
          *(bf16x4*)&sT2[lane32*256 + f0] = o;
        }
      }
    }
  }
  __syncthreads();                    // sT2 ready; sPool reads done

  // ---- mlp0 (x-half + t2), mlp1, mlp2 ----
  layerT<1,0,1>(sAct, wbuf, sT2, mw0, 512, mlp_b0,    maskp, blk, w, lane32, hi, tid);
  layerT<1,0,0>(sAct, wbuf, sT2, mw1, 256, mlp_b1,    maskp, blk, w, lane32, hi, tid);
  layerT<0,1,0>(sAct, wbuf, sT2, mw2, 256, mlp_bias2, maskp, blk, w, lane32, hi, tid);

  __syncthreads();                    // mlp2 compute done
  poolT(sAct, sPool, tid);
  __syncthreads();                    // pool2 visible (also: all sAct reads done)

  // ---- out0: y = relu(pooled @ out_w0^T + b0) -> sY rows 0..11 (aliases sAct) ----
  {
    bf16x8 Bp[16];
    #pragma unroll
    for (int t = 0; t < 16; ++t)
      Bp[t] = *(const bf16x8*)&sPool[AADDR(lane32, 2*t + hi)];
    #pragma unroll 1
    for (int m = 0; m < 2; ++m){
      int nt = w*2 + m;
      f32x16 acc = {};
      #pragma unroll
      for (int t = 0; t < 16; ++t){
        bf16x8 wf = *(const bf16x8*)(ow0 + (size_t)(nt*32 + lane32)*256 + 16*t + 8*hi);
        acc = __builtin_amdgcn_mfma_f32_32x32x16_bf16(wf, Bp[t], acc, 0, 0, 0);
      }
      if (lane32 < 12){
        #pragma unroll
        for (int q2 = 0; q2 < 4; ++q2){
          int f0 = nt*32 + 8*q2 + 4*hi;
          f32x4 bb = *(const f32x4*)(out_b0 + f0);
          bf16x4 o;
          #pragma unroll
          for (int j = 0; j < 4; ++j) o[j] = f2b(fmaxf(acc[4*q2 + j] + bb[j], 0.0f));
          *(bf16x4*)&sY[lane32*256 + (((nt*4 + q2) ^ (lane32 & 31))<<3) + 4*hi] = o;
        }
      }
    }
  }
  __syncthreads();                    // y visible

  // ---- out1: z = (y @ out_w1^T + b1) * valid -> global fp32 ----
  {
    bf16x8 By[16];
    #pragma unroll
    for (int t = 0; t < 16; ++t)
      By[t] = *(const bf16x8*)&sY[AADDR(lane32, 2*t + hi)];
    #pragma unroll 1
    for (int m = 0; m < 2; ++m){
      int nt = w*2 + m;
      f32x16 acc = {};
      #pragma unroll
      for (int t = 0; t < 16; ++t){
        bf16x8 wf = *(const bf16x8*)(ow1 + (size_t)(nt*32 + lane32)*256 + 16*t + 8*hi);
        acc = __builtin_amdgcn_mfma_f32_32x32x16_bf16(wf, By[t], acc, 0, 0, 0);
      }
      int gp = blk*12 + lane32;
      if (lane32 < 12 && gp < NPOLY){
        float vd = sValid[lane32];
        #pragma unroll
        for (int q2 = 0; q2 < 4; ++q2){
          int f0 = nt*32 + 8*q2 + 4*hi;
          f32x4 bb = *(const f32x4*)(out_b1 + f0);
          f32x4 o;
          #pragma unroll
          for (int j = 0; j < 4; ++j) o[j] = (acc[4*q2 + j] + bb[j]) * vd;
          *(f32x4*)&outp[(size_t)gp*256 + f0] = o;
        }
      }
    }
  }
}

extern "C" void kernel_launch(void* const* d_in, const int* in_sizes, int n_in,
                              void* d_out, int out_size, void* d_ws, size_t ws_size,
                              hipStream_t stream)
{
  const float* poly      = (const float*)d_in[0];
  const int*   maskp     = (const int*)  d_in[1];
  const float* pre_w0    = (const float*)d_in[2];
  const float* pre_g0    = (const float*)d_in[3];
  const float* pre_b0    = (const float*)d_in[4];
  const float* pre_w1    = (const float*)d_in[5];
  const float* pre_g1    = (const float*)d_in[6];
  const float* pre_b1    = (const float*)d_in[7];
  const float* pre_w2    = (const float*)d_in[8];
  const float* pre_bias2 = (const float*)d_in[9];
  const float* mlp_w0    = (const float*)d_in[10];
  const float* mlp_g0    = (const float*)d_in[11];
  const float* mlp_b0    = (const float*)d_in[12];
  const float* mlp_w1    = (const float*)d_in[13];
  const float* mlp_g1    = (const float*)d_in[14];
  const float* mlp_b1    = (const float*)d_in[15];
  const float* mlp_w2    = (const float*)d_in[16];
  const float* mlp_bias2 = (const float*)d_in[17];
  const float* out_w0    = (const float*)d_in[18];
  const float* out_b0    = (const float*)d_in[19];
  const float* out_w1    = (const float*)d_in[20];
  const float* out_b1    = (const float*)d_in[21];

  bf16* ws = (bf16*)d_ws;   // 1,064,960 B of ws used

  (void)hipFuncSetAttribute((const void*)&traj_kernel,
                            hipFuncAttributeMaxDynamicSharedMemorySize, LDS_TOTAL);

  prep_kernel<<<dim3(64, 8), dim3(256), 0, stream>>>(
      pre_w0, pre_w1, pre_w2, mlp_w0, mlp_w1, mlp_w2, out_w0, out_w1,
      pre_g0, pre_g1, mlp_g0, mlp_g1, ws);

  traj_kernel<<<dim3(683), dim3(256), LDS_TOTAL, stream>>>(
      poly, maskp,
      pre_b0, pre_b1, pre_bias2,
      mlp_b0, mlp_b1, mlp_bias2,
      out_b0, out_b1,
      ws, (float*)d_out);
}